// Round 7
// baseline (526.359 us; speedup 1.0000x reference)
//
#include <hip/hip_runtime.h>
#include <stdint.h>

// Problem constants (B=2, Nr=40962, in_ch=128, out_ch=64). FP32 I/O.
#define NR     40962
#define NH     163842      // 4*NR-6
#define NR7    286734      // NR*7
#define M_UP   40962
#define M_CV   327684      // B*NH
#define BN_EPS 1e-5f
#define SLOPE  0.2f

typedef __attribute__((ext_vector_type(8))) short  short8;
typedef __attribute__((ext_vector_type(4))) float  f32x4;
typedef unsigned short ushort_t;

__device__ __forceinline__ ushort_t f2bf(float f) {
  union { float f; uint32_t u; } v; v.f = f;
  uint32_t r = v.u + 0x7fffu + ((v.u >> 16) & 1u);  // RNE
  return (ushort_t)(r >> 16);
}
__device__ __forceinline__ float bf2f(ushort_t h) {
  union { uint32_t u; float f; } v; v.u = ((uint32_t)h) << 16;
  return v.f;
}
__device__ __forceinline__ int clampi(int v, int hi) {
  v = v < 0 ? 0 : v;
  return v >= hi ? hi - 1 : v;
}

// Async global->LDS, 16B/lane. LDS dest = wave-uniform base + lane*16.
__device__ __forceinline__ void gload_lds16(const void* g, void* l) {
  __builtin_amdgcn_global_load_lds(
      (__attribute__((address_space(1))) void*)(void*)g,
      (__attribute__((address_space(3))) void*)l, 16, 0, 0);
}

// ---------------------------------------------------------------------------
// Gather-GEMM, 256x64 tile, 8 waves (512 thr), 32 rows/wave.
// j-unit = one neighbor: each wave stages its 32 rows' FULL rows (256B for
// conv1 -> 256-B DRAM bursts instead of isolated 128-B lines; 128B conv2)
// via global_load_lds, LDS double-buffered, with HAND-COUNTED vmcnt waits:
//   per j: issue W(j+1) [NW scalar], issue A(j+1) [NI gll]; vmcnt(NW+NI)
//   -> A(j) landed (A(j+1)+W fly); compute; lgkm-barrier; vmcnt(NI) -> W
//   landed (A(j+1) flies); writeB; lgkm-barrier.  vmcnt NEVER drains in-loop.
// Conflict-freedom: per-lane SOURCE pre-swizzle s^=(w&7) with linear gll
// dest (rule 21); reads/writes of A and B spread 8-way by construction.
// Neighbor indices staged once to LDS (Ns) -> index reads are lgkm-domain
// (no vmcnt pollution). No per-thread A registers -> no AGPR parking.
// MODE 0: dense A bf16 [M][128], K=128 (up-GEMM), NJ=1.
// MODE 1: conv1, row=xcat[idx][128 elems], K=7*128, out bf16.
// MODE 2: conv2, row=y1[idx][64 elems],   K=7*64,  out fp32.
// LDS: M1 8K(Ns)+128K(A)+16K(B)=152K (1 blk/CU); M2 80K (2 blk/CU); M0 80K.
// FSTATS: fused per-channel sum/sumsq -> statsPart[16 slices][128].
// ---------------------------------------------------------------------------
template<int MODE, bool FSTATS>
__global__ __launch_bounds__(512, 2) void gemm_conv(
    const ushort_t* __restrict__ Asrc,
    const int*      __restrict__ neigh,
    const float*    __restrict__ Wf,     // fp32 [K][NWc]
    const float*    __restrict__ bias,
    void*           __restrict__ OutV,
    float*          __restrict__ statsPart,
    int M, int NWc)
{
  constexpr int KJ   = (MODE == 2) ? 64 : 128;  // k-elems per j-unit
  constexpr int NJ   = (MODE == 0) ? 1 : 7;
  constexpr int H    = KJ / 64;
  constexpr int ROWB = KJ * 2;        // row bytes
  constexpr int SPR  = KJ / 8;        // 16B slots per row
  constexpr int RPI  = 64 / SPR;      // rows per gll instruction
  constexpr int NI   = 32 / RPI;      // gll instrs per wave per j
  constexpr int NU   = SPR / 8;       // writeB units per thread
  constexpr int NW   = NU * 8;        // W scalar loads per thread per j
  constexpr int NBUF = (MODE == 0) ? 1 : 2;
  constexpr int ASZ  = 32 * ROWB;     // per-wave per-buf A bytes
  constexpr int AOFF = (MODE == 0) ? 0 : 8192;
  constexpr int BOFF = AOFF + 8 * NBUF * ASZ;
  constexpr int ROWE = (MODE == 2) ? 64 : 128;  // A row length (elems)

  __shared__ __align__(16) char smem[BOFF + 64 * ROWB];
  int* NsI = (int*)smem;              // [256 rows][8] gathered row index

  const int tid  = threadIdx.x;
  const int wv   = tid >> 6;          // 0..7
  const int lane = tid & 63;
  const int r16  = lane & 15;
  const int q    = lane >> 4;
  const int r7   = r16 & 7;
  const int mTile = blockIdx.y * 256;
  const int nTile = blockIdx.x * 64;
  const int Awv  = AOFF + wv * NBUF * ASZ;

  f32x4 acc[2][4];
#pragma unroll
  for (int a = 0; a < 2; ++a)
#pragma unroll
    for (int i = 0; i < 4; ++i) acc[a][i] = (f32x4){0.f, 0.f, 0.f, 0.f};

  float wreg[NW];

  // W loads for j-unit (coalesced 256B rows of W); kept in regs until writeB.
  auto loadW = [&](int j) {
#pragma unroll
    for (int v = 0; v < NU; ++v) {
      const int unit = tid + 512 * v;
      const int n = unit & 63, sl = unit >> 6;
#pragma unroll
      for (int u = 0; u < 8; ++u)
        wreg[v * 8 + u] = Wf[(size_t)(j * KJ + sl * 8 + u) * NWc + nTile + n];
    }
  };
  // wreg -> Bs bf16, 16B slots XOR-swizzled by (n&7).
  auto writeB = [&]() {
#pragma unroll
    for (int v = 0; v < NU; ++v) {
      const int unit = tid + 512 * v;
      const int n = unit & 63, sl = unit >> 6;
      short8 o;
#pragma unroll
      for (int u = 0; u < 8; ++u) o[u] = (short)f2bf(wreg[v * 8 + u]);
      *(short8*)(smem + BOFF + n * ROWB + ((sl ^ (n & 7)) * 16)) = o;
    }
  };

  // Stage A j-unit into buf: NI gll, RPI rows per instr, full rows.
  // Source slot pre-swizzled (s^(w&7)) so linear LDS dest reads conflict-free.
  auto stageA = [&](int buf, int j) {
    const int r = lane / SPR;
    const int s = lane % SPR;
#pragma unroll
    for (int i = 0; i < NI; ++i) {
      const int w = i * RPI + r;           // 0..31
      size_t rowE;
      if constexpr (MODE == 0) {
        int gr = mTile + wv * 32 + w; if (gr >= M) gr = M - 1;
        rowE = (size_t)gr * 128;
      } else {
        rowE = (size_t)NsI[(wv * 32 + w) * 8 + j] * ROWE;
      }
      const int sp = s ^ (w & 7);
      gload_lds16(Asrc + rowE + sp * 8,
                  smem + Awv + buf * ASZ + i * 1024);
    }
  };

  auto compute = [&](int buf) {
    const char* Ab = smem + Awv + buf * ASZ;
    const char* Bb = smem + BOFF;
#pragma unroll
    for (int h = 0; h < H; ++h) {
#pragma unroll
      for (int ks = 0; ks < 2; ++ks) {
        const int e  = h * 8 + ks * 4 + q;
        const int sw = (e ^ r7) * 16;
        const short8 a0 = *(const short8*)(Ab + r16 * ROWB + sw);
        const short8 a1 = *(const short8*)(Ab + (16 + r16) * ROWB + sw);
#pragma unroll
        for (int ct = 0; ct < 4; ++ct) {
          const short8 b = *(const short8*)(Bb + (ct * 16 + r16) * ROWB + sw);
          acc[0][ct] = __builtin_amdgcn_mfma_f32_16x16x32_bf16(a0, b, acc[0][ct], 0, 0, 0);
          acc[1][ct] = __builtin_amdgcn_mfma_f32_16x16x32_bf16(a1, b, acc[1][ct], 0, 0, 0);
        }
      }
    }
  };

  // ---- prologue ----
  if constexpr (MODE != 0) {
    for (int i = tid; i < 2048; i += 512) {
      const int w = i >> 3, jj = i & 7;
      if (jj < 7) {
        int rr = mTile + w; if (rr >= M) rr = M - 1;
        const int gb = (rr >= NH) ? 1 : 0;
        const int gn = rr - gb * NH;
        NsI[i] = gb * NH + clampi(neigh[gn * 7 + jj], NH);
      }
    }
  }
  loadW(0);
  if constexpr (MODE != 0) {
    asm volatile("s_waitcnt lgkmcnt(0)" ::: "memory");
    __builtin_amdgcn_s_barrier();          // Ns visible; W rides through
  }
  stageA(0, 0);
  asm volatile("s_waitcnt vmcnt(%0)" :: "n"(NI) : "memory");  // W(0) done
  writeB();
  asm volatile("s_waitcnt lgkmcnt(0)" ::: "memory");
  __builtin_amdgcn_s_barrier();            // Bs(0) visible; A(0) in flight

  // ---- main loop: one j-unit per iteration, vmcnt never drained ----
#pragma unroll
  for (int j = 0; j < NJ; ++j) {
    const int buf = (MODE == 0) ? 0 : (j & 1);
    if (j + 1 < NJ) {
      loadW(j + 1);
      __builtin_amdgcn_sched_barrier(0);
      stageA(buf ^ 1, j + 1);
      __builtin_amdgcn_sched_barrier(0);
      asm volatile("s_waitcnt vmcnt(%0)" :: "n"(NW + NI) : "memory"); // A(j) in
    } else {
      asm volatile("s_waitcnt vmcnt(0)" ::: "memory");
    }
    __builtin_amdgcn_sched_barrier(0);
    compute(buf);
    if (j + 1 < NJ) {
      asm volatile("s_waitcnt lgkmcnt(0)" ::: "memory");
      __builtin_amdgcn_s_barrier();        // all waves done reading Bs(j)
      asm volatile("s_waitcnt vmcnt(%0)" :: "n"(NI) : "memory"); // W(j+1) in
      writeB();
      asm volatile("s_waitcnt lgkmcnt(0)" ::: "memory");
      __builtin_amdgcn_s_barrier();        // Bs(j+1) visible; A(j+1) flies
    }
  }

  // epilogue: C/D layout col=lane&15, row=(lane>>4)*4+reg
  float s1a[4] = {0.f, 0.f, 0.f, 0.f};
  float s2a[4] = {0.f, 0.f, 0.f, 0.f};
#pragma unroll
  for (int ct = 0; ct < 4; ++ct) {
    const int colg = nTile + ct * 16 + r16;
    const float bv = bias[colg];
#pragma unroll
    for (int rg = 0; rg < 2; ++rg) {
#pragma unroll
      for (int i = 0; i < 4; ++i) {
        const int rowg = mTile + wv * 32 + rg * 16 + q * 4 + i;
        const float y = acc[rg][ct][i] + bv;
        if (rowg < M) {
          if constexpr (MODE == 2)
            ((float*)OutV)[(size_t)rowg * NWc + colg] = y;
          else
            ((ushort_t*)OutV)[(size_t)rowg * NWc + colg] = f2bf(y);
          if constexpr (FSTATS) { s1a[ct] += y; s2a[ct] += y * y; }
        }
      }
    }
  }

  if constexpr (FSTATS) {
    __syncthreads();                       // all LDS use done; reuse B region
    float* Sred  = (float*)(smem + BOFF);  // [8 waves][64 ch]
    float* S2red = Sred + 512;
#pragma unroll
    for (int ct = 0; ct < 4; ++ct) {
      float v = s1a[ct], w = s2a[ct];
      v += __shfl_xor(v, 16, 64); v += __shfl_xor(v, 32, 64);
      w += __shfl_xor(w, 16, 64); w += __shfl_xor(w, 32, 64);
      if (q == 0) {
        Sred[wv * 64 + ct * 16 + r16]  = v;
        S2red[wv * 64 + ct * 16 + r16] = w;
      }
    }
    __syncthreads();
    if (tid < 64) {
      float v = 0.f, w = 0.f;
#pragma unroll
      for (int i = 0; i < 8; ++i) {
        v += Sred[i * 64 + tid];
        w += S2red[i * 64 + tid];
      }
      float* p = statsPart + (size_t)(blockIdx.y & 15) * 128;
      atomicAdd(&p[tid], v);
      atomicAdd(&p[64 + tid], w);
    }
  }
}

// ---------------------------------------------------------------------------
// Per batch: units [0, NH*8) build xup into LOW 64 channels of xcat rows;
// units [NH*8, NH*16) convert x2 (this batch) into HIGH 64 channels.
// ---------------------------------------------------------------------------
__global__ __launch_bounds__(256) void build_xup_x2_kernel(
    const ushort_t* __restrict__ h, const int* __restrict__ top,
    const int* __restrict__ down, const float* __restrict__ x2b,
    ushort_t* __restrict__ xcatB, long long total)
{
  const long long gid = (long long)blockIdx.x * 256 + threadIdx.x;
  if (gid >= total) return;
  if (gid < (long long)NH * 8) {
    const int n  = (int)(gid >> 3);
    const int c0 = (int)(gid & 7) * 8;
    short8 v;
    if (n < NR) {
      const int idx = clampi(top[n], NR7);
      v = *(const short8*)(h + (size_t)idx * 64 + c0);
    } else {
      const int d  = n - NR;
      const int i0 = clampi(down[d * 2], NR7);
      const int i1 = clampi(down[d * 2 + 1], NR7);
      short8 u0 = *(const short8*)(h + (size_t)i0 * 64 + c0);
      short8 u1 = *(const short8*)(h + (size_t)i1 * 64 + c0);
#pragma unroll
      for (int i = 0; i < 8; ++i)
        v[i] = (short)f2bf(0.5f * (bf2f((ushort_t)u0[i]) + bf2f((ushort_t)u1[i])));
    }
    *(short8*)(xcatB + (size_t)n * 128 + c0) = v;
  } else {
    const long long g2 = gid - (long long)NH * 8;
    const int n  = (int)(g2 >> 3);
    const int c0 = (int)(g2 & 7) * 8;
    const f32x4 f0 = *(const f32x4*)(x2b + (size_t)n * 64 + c0);
    const f32x4 f1 = *(const f32x4*)(x2b + (size_t)n * 64 + c0 + 4);
    short8 v;
#pragma unroll
    for (int i = 0; i < 4; ++i) {
      v[i]     = (short)f2bf(f0[i]);
      v[i + 4] = (short)f2bf(f1[i]);
    }
    *(short8*)(xcatB + (size_t)n * 128 + 64 + c0) = v;
  }
}

// x1 fp32 -> bf16 dense [40962][128]
__global__ __launch_bounds__(256) void cvt_bf_kernel(
    const float* __restrict__ src, ushort_t* __restrict__ dst, long long n8)
{
  const long long gid = (long long)blockIdx.x * 256 + threadIdx.x;
  if (gid >= n8) return;
  const f32x4 f0 = *(const f32x4*)(src + gid * 8);
  const f32x4 f1 = *(const f32x4*)(src + gid * 8 + 4);
  short8 v;
#pragma unroll
  for (int i = 0; i < 4; ++i) {
    v[i]     = (short)f2bf(f0[i]);
    v[i + 4] = (short)f2bf(f1[i]);
  }
  *(short8*)(dst + gid * 8) = v;
}

__global__ __launch_bounds__(256) void zero_kernel(float* __restrict__ p, int n) {
  const int gid = blockIdx.x * 256 + threadIdx.x;
  if (gid < n) p[gid] = 0.f;
}

// Fallback stats over fp32 buffer -> 16 partial slices
__global__ __launch_bounds__(256) void stats_f32_kernel(
    const float* __restrict__ buf, float* __restrict__ part, int rows)
{
  const int tid = threadIdx.x;
  const int c   = tid & 63;
  const int rl  = tid >> 6;
  float s = 0.f, s2 = 0.f;
  for (int r = blockIdx.x * 4 + rl; r < rows; r += gridDim.x * 4) {
    const float v = buf[(size_t)r * 64 + c];
    s += v; s2 += v * v;
  }
  __shared__ float sh[2][256];
  sh[0][tid] = s; sh[1][tid] = s2;
  __syncthreads();
  if (tid < 64) {
#pragma unroll
    for (int i = 1; i < 4; ++i) { s += sh[0][tid + 64 * i]; s2 += sh[1][tid + 64 * i]; }
    float* p = part + (size_t)(blockIdx.x & 15) * 128;
    atomicAdd(&p[c], s);
    atomicAdd(&p[64 + c], s2);
  }
}

// Fallback stats over bf16 buffer -> 16 partial slices
__global__ __launch_bounds__(256) void stats_bf16_kernel(
    const ushort_t* __restrict__ buf, float* __restrict__ part, int rows)
{
  const int tid = threadIdx.x;
  const int c   = tid & 63;
  const int rl  = tid >> 6;
  float s = 0.f, s2 = 0.f;
  for (int r = blockIdx.x * 4 + rl; r < rows; r += gridDim.x * 4) {
    const float v = bf2f(buf[(size_t)r * 64 + c]);
    s += v; s2 += v * v;
  }
  __shared__ float sh[2][256];
  sh[0][tid] = s; sh[1][tid] = s2;
  __syncthreads();
  if (tid < 64) {
#pragma unroll
    for (int i = 1; i < 4; ++i) { s += sh[0][tid + 64 * i]; s2 += sh[1][tid + 64 * i]; }
    float* p = part + (size_t)(blockIdx.x & 15) * 128;
    atomicAdd(&p[c], s);
    atomicAdd(&p[64 + c], s2);
  }
}

// Reduce 16 partial slices -> final [sc[64] | sh[64]] at part+2048
__global__ void finalize_kernel(float* __restrict__ part,
                                const float* __restrict__ gamma,
                                const float* __restrict__ beta)
{
  const int c = threadIdx.x;  // 64
  float s = 0.f, s2 = 0.f;
  for (int i = 0; i < 16; ++i) { s += part[i * 128 + c]; s2 += part[i * 128 + 64 + c]; }
  const float invN = 1.0f / (float)M_CV;
  const float mean = s * invN;
  float var = fmaxf(s2 * invN - mean * mean, 0.f);
  const float sc = gamma[c] * rsqrtf(var + BN_EPS);
  float* fin = part + 2048;
  fin[c] = sc;
  fin[64 + c] = beta[c] - mean * sc;
}

// In-place y = lrelu(v*sc[c] + sh[c]); fin = [sc[64] | sh[64]]
template<bool F32>
__global__ __launch_bounds__(256) void bnl_kernel(
    void* __restrict__ bufV, const float* __restrict__ fin, long long nvec)
{
  const long long gid = (long long)blockIdx.x * 256 + threadIdx.x;
  if (gid >= nvec) return;
  if constexpr (F32) {
    float* buf = (float*)bufV;
    const int c0 = (int)((gid * 4) & 63);
    f32x4 v = *(f32x4*)(buf + gid * 4);
#pragma unroll
    for (int i = 0; i < 4; ++i) {
      const float y = v[i] * fin[c0 + i] + fin[64 + c0 + i];
      v[i] = (y >= 0.f) ? y : SLOPE * y;
    }
    *(f32x4*)(buf + gid * 4) = v;
  } else {
    ushort_t* buf = (ushort_t*)bufV;
    const int c0 = (int)((gid * 8) & 63);
    short8 v = *(short8*)(buf + gid * 8);
#pragma unroll
    for (int i = 0; i < 8; ++i) {
      float y = bf2f((ushort_t)v[i]) * fin[c0 + i] + fin[64 + c0 + i];
      y = (y >= 0.f) ? y : SLOPE * y;
      v[i] = (short)f2bf(y);
    }
    *(short8*)(buf + gid * 8) = v;
  }
}

// ---------------------------------------------------------------------------
extern "C" void kernel_launch(void* const* d_in, const int* in_sizes, int n_in,
                              void* d_out, int out_size, void* d_ws, size_t ws_size,
                              hipStream_t stream)
{
  const float* x1   = (const float*)d_in[0];
  const float* x2   = (const float*)d_in[1];
  const int*   neigh= (const int*)d_in[2];
  const int*   top  = (const int*)d_in[3];
  const int*   down = (const int*)d_in[4];
  const float* upW  = (const float*)d_in[5];
  const float* upb  = (const float*)d_in[6];
  const float* c1W  = (const float*)d_in[7];
  const float* c1b  = (const float*)d_in[8];
  const float* g1   = (const float*)d_in[9];
  const float* b1   = (const float*)d_in[10];
  const float* c2W  = (const float*)d_in[11];
  const float* c2b  = (const float*)d_in[12];
  const float* g2   = (const float*)d_in[13];
  const float* b2   = (const float*)d_in[14];

  // d_out (83,887,104 B) staging plan:
  //   [0, 83886080)  xcat bf16 [B*NH][128]: cols 0:64 = xup, 64:128 = bf16(x2)
  //   x1bf (10,486,272 B) overlays the start of batch-b's xcat region; dead
  //   before build_xup_x2 writes there (strictly sequential stream).
  //   xcat dead after conv1 -> out fp32 reuses d_out.
  // ws: y1 bf16 [B*NH][64] = 41,943,552 (h bf16 36.7MB overlays it in phase 1).
  //   Gated tail (+17,408 B): st1 (8,704) + st2 (8,704).
  // Weights read fp32 directly from d_in inside the GEMMs (no Wt staging room).
  char* dob = (char*)d_out;
  ushort_t* xcat = (ushort_t*)dob;
  float*    outb = (float*)d_out;
  ushort_t* hbuf = (ushort_t*)d_ws;
  ushort_t* ybuf = (ushort_t*)d_ws;

  const bool gated = ws_size >= (size_t)(41943552 + 17408);
  float* st1 = gated ? (float*)((char*)d_ws + 41943552) : (float*)d_out;
  float* st2 = gated ? (float*)((char*)d_ws + 41943552 + 8704) : (float*)d_ws;

  if (gated) zero_kernel<<<17, 256, 0, stream>>>(st1, 4352);  // st1+st2 adjacent

  // Phase 1 — per batch: x1->bf16 (overlay); h = x1bf @ upW + upb;
  //           xup + bf16(x2) -> xcat (merged kernel)
  for (int b = 0; b < 2; ++b) {
    ushort_t* x1bf = xcat + (size_t)b * NH * 128;
    cvt_bf_kernel<<<2561, 256, 0, stream>>>(x1 + (size_t)b * M_UP * 128,
                                            x1bf, 655392LL);
    gemm_conv<0, false><<<dim3(7, 161), 512, 0, stream>>>(
        x1bf, nullptr, upW, upb, hbuf, nullptr, M_UP, 448);
    build_xup_x2_kernel<<<10241, 256, 0, stream>>>(
        hbuf, top, down, x2 + (size_t)b * NH * 64,
        xcat + (size_t)b * NH * 128, (long long)NH * 16);
  }

  // Phase 2 — y1 = meshconv1(xcat) -> ws (+ fused BN1 stats if gated)
  if (gated) {
    gemm_conv<1, true><<<dim3(1, 1281), 512, 0, stream>>>(
        xcat, neigh, c1W, c1b, ybuf, st1, M_CV, 64);
  } else {
    gemm_conv<1, false><<<dim3(1, 1281), 512, 0, stream>>>(
        xcat, neigh, c1W, c1b, ybuf, nullptr, M_CV, 64);
    zero_kernel<<<9, 256, 0, stream>>>(st1, 2176);     // xcat dead now
    stats_bf16_kernel<<<2048, 256, 0, stream>>>(ybuf, st1, M_CV);
  }
  finalize_kernel<<<1, 64, 0, stream>>>(st1, g1, b1);
  bnl_kernel<false><<<10241, 256, 0, stream>>>(ybuf, st1 + 2048, 2621472LL);

  // Phase 3 — out = meshconv2(y1) -> d_out fp32 (+ fused BN2 stats if gated)
  if (gated) {
    gemm_conv<2, true><<<dim3(1, 1281), 512, 0, stream>>>(
        ybuf, neigh, c2W, c2b, outb, st2, M_CV, 64);
  } else {
    gemm_conv<2, false><<<dim3(1, 1281), 512, 0, stream>>>(
        ybuf, neigh, c2W, c2b, outb, nullptr, M_CV, 64);
    zero_kernel<<<9, 256, 0, stream>>>(st2, 2176);     // y1 dead now
    stats_f32_kernel<<<2048, 256, 0, stream>>>(outb, st2, M_CV);
  }
  finalize_kernel<<<1, 64, 0, stream>>>(st2, g2, b2);
  bnl_kernel<true><<<20481, 256, 0, stream>>>(outb, st2 + 2048, 5242944LL);
}